// Round 15
// baseline (1766.867 us; speedup 1.0000x reference)
//
#include <hip/hip_runtime.h>
#include <hip/hip_bf16.h>

#define TT 2048
#define BB 512
#define HH 64
#define L2E 1.44269504088896340736f

typedef _Float16 h2 __attribute__((ext_vector_type(2)));
typedef _Float16 f16x8 __attribute__((ext_vector_type(8)));
typedef float f32x4 __attribute__((ext_vector_type(4)));

__device__ __forceinline__ float frcp(float x){ return __builtin_amdgcn_rcpf(x); }
__device__ __forceinline__ float fexp2(float x){ return __builtin_amdgcn_exp2f(x); }
__device__ __forceinline__ float fsig(float a){ return frcp(1.0f + __expf(-a)); }
__device__ __forceinline__ float ftanh(float a){ return 1.0f - 2.0f*frcp(__expf(2.0f*a)+1.0f); }
__device__ __forceinline__ h2 pk16(float lo, float hi){
  return __builtin_bit_cast(h2, __builtin_amdgcn_cvt_pkrtz(lo, hi));
}
__device__ __forceinline__ int pk16i(float lo, float hi){
  return __builtin_bit_cast(int, pk16(lo, hi));
}

// MFMA, TWO REAL ROWS per block (R13 post-mortem: formulation numerically
// verified but 1 row wasted the M dimension; 1790 cyc/step of mostly serial
// chain). M-slots 0,1 carry batch rows b0, b0+1:
//   A-layout row = l&15 -> lanes read h/x of row (l&1) (rows 2-15 garbage,
//   multiplied by zero B or their C rows unused).
//   C-layout: row = (l>>4)*4+reg -> lanes 0-15 hold row 0 in reg0, row 1 in
//   reg1 of every acc tile.
// Latency fixes vs R13: x-tile MFMAs FIRST from a persistent zero quad (they
// depend only on prefetched xs[t], so they fill the h write->read turnaround;
// h-dependent chain is now 2 MFMAs deep, not 3); x unconditional read
// (B fragment already zero for k>=8); x prefetched one step ahead.
__global__ void __launch_bounds__(64)
__attribute__((amdgpu_waves_per_eu(1, 1)))
lstm_fwd_kernel(
    const float* __restrict__ x, const float* __restrict__ Wih,
    const float* __restrict__ Whh, const float* __restrict__ bih,
    const float* __restrict__ bhh, float* __restrict__ hout)
{
  const int b0 = blockIdx.x * 2;
  const int l  = threadIdx.x;
  const int ln = l & 15;          // N index within tile (gate col)
  const int kg = l >> 4;          // K group (8 f16 per group)

  __shared__ int4 xs[2][TT];      // x packed f16 per row: 64 KB
  __shared__ int4 hh4[16];        // h f16[2][64] = 256 B (16B-aligned)

  // ---- one-time: stage x of both rows as packed f16 (+1.0 bias slot) ----
  #pragma unroll 1
  for (int r = 0; r < 2; ++r){
    #pragma unroll 1
    for (int it = 0; it < TT/64; ++it){
      const int t = it*64 + l;
      const float* p = x + ((size_t)(b0+r)*TT + t)*7;
      int4 v;
      v.x = pk16i(p[0], p[1]);
      v.y = pk16i(p[2], p[3]);
      v.z = pk16i(p[4], p[5]);
      v.w = pk16i(p[6], 1.0f);
      xs[r][t] = v;
    }
  }
  if (l < 16) hh4[l] = int4{0,0,0,0};   // h_0 = 0 for both rows

  // ---- B fragments (loop-invariant MFMA operands -> AGPR-resident) ----
  // bf[nt][kt]: n = nt*16+ln, k = kt*32 + kg*8 + j. kt=2: [Wih ; bias ; 0].
  // Pre-scaled by -log2e (g rows by -2log2e) for exp2 activations.
  int4 bf[16][3];
  #pragma unroll
  for (int nt = 0; nt < 16; ++nt){
    const int n = nt*16 + ln;
    const float sq = ((n >> 6) == 2) ? (-2.0f*L2E) : (-L2E);
    const float* wr = Whh + (size_t)n*HH;
    #pragma unroll
    for (int kt = 0; kt < 2; ++kt){
      const int kb = kt*32 + kg*8;
      int4 v;
      v.x = pk16i(wr[kb+0]*sq, wr[kb+1]*sq);
      v.y = pk16i(wr[kb+2]*sq, wr[kb+3]*sq);
      v.z = pk16i(wr[kb+4]*sq, wr[kb+5]*sq);
      v.w = pk16i(wr[kb+6]*sq, wr[kb+7]*sq);
      bf[nt][kt] = v;
    }
    int4 v2 = int4{0,0,0,0};
    if (kg == 0){
      const float* wi = Wih + (size_t)n*7;
      v2.x = pk16i(wi[0]*sq, wi[1]*sq);
      v2.y = pk16i(wi[2]*sq, wi[3]*sq);
      v2.z = pk16i(wi[4]*sq, wi[5]*sq);
      v2.w = pk16i(wi[6]*sq, (bih[n] + bhh[n])*sq);
    }
    bf[nt][2] = v2;
  }

  const f32x4 zeroq = {0.f, 0.f, 0.f, 0.f};
  float cst[2][4] = {{0,0,0,0},{0,0,0,0}};   // c per row, units 16j+ln
  float hval[2][4];

  // prologue: x of t=0 preloaded
  int4 a2c = xs[l & 1][0];

  #pragma unroll 1
  for (int t = 0; t < TT; ++t){
    // prefetch next x (consumed next iteration; wait folds into a0/a1 wait)
    const int4 a2n = xs[l & 1][(t+1) & (TT-1)];

    // x-tile MFMAs from zero: independent of h -> fill h-roundtrip latency
    f32x4 acc[16];
    #pragma unroll
    for (int nt = 0; nt < 16; ++nt)
      acc[nt] = __builtin_amdgcn_mfma_f32_16x16x32_f16(
          __builtin_bit_cast(f16x8, a2c), __builtin_bit_cast(f16x8, bf[nt][2]),
          zeroq, 0, 0, 0);

    // h fragments (written end of previous step; same-wave in-order DS)
    const char* hb = reinterpret_cast<const char*>(hh4);
    const int4 a0 = *reinterpret_cast<const int4*>(hb + (l&1)*128 + kg*16);
    const int4 a1 = *reinterpret_cast<const int4*>(hb + (l&1)*128 + 64 + kg*16);

    #pragma unroll
    for (int nt = 0; nt < 16; ++nt)
      acc[nt] = __builtin_amdgcn_mfma_f32_16x16x32_f16(
          __builtin_bit_cast(f16x8, a0), __builtin_bit_cast(f16x8, bf[nt][0]),
          acc[nt], 0, 0, 0);
    #pragma unroll
    for (int nt = 0; nt < 16; ++nt)
      acc[nt] = __builtin_amdgcn_mfma_f32_16x16x32_f16(
          __builtin_bit_cast(f16x8, a1), __builtin_bit_cast(f16x8, bf[nt][1]),
          acc[nt], 0, 0, 0);

    // activations: lanes 0-15 hold row r in acc[..][r]; unit u = 16j+ln.
    #pragma unroll
    for (int r = 0; r < 2; ++r){
      #pragma unroll
      for (int j = 0; j < 4; ++j){
        const float iv = frcp(1.0f + fexp2(acc[ 0+j][r]));
        const float fv = frcp(1.0f + fexp2(acc[ 4+j][r]));
        const float gv = 2.0f*frcp(1.0f + fexp2(acc[ 8+j][r])) - 1.0f;
        const float ov = frcp(1.0f + fexp2(acc[12+j][r]));
        const float cc = fv*cst[r][j] + iv*gv;
        cst[r][j] = cc;
        const float rr = frcp(1.0f + fexp2(cc*(-2.0f*L2E)));
        hval[r][j] = 2.0f*ov*rr - ov;
      }
    }

    // publish h_t: lanes 0-15 write 8 b16 (2 rows x 4 unit groups)
    if (l < 16){
      unsigned short* hs = reinterpret_cast<unsigned short*>(hh4);
      #pragma unroll
      for (int r = 0; r < 2; ++r)
        #pragma unroll
        for (int j = 0; j < 4; ++j)
          hs[r*64 + 16*j + ln] =
              __builtin_bit_cast(unsigned short, (_Float16)hval[r][j]);
    }
    a2c = a2n;
  }

  if (l < 16){
    #pragma unroll
    for (int r = 0; r < 2; ++r)
      #pragma unroll
      for (int j = 0; j < 4; ++j)
        hout[(b0+r)*HH + 16*j + ln] = hval[r][j];
  }
}

// Backward direction contributes only ONE step (scan reverse=True: output at
// t=T-1 is the first reverse step from zero state => W_hh_b unused, c = i*g).
// Fused with the final linear layer.
__global__ __launch_bounds__(64, 1) void lstm_bwd_lin_kernel(
    const float* __restrict__ x,   const float* __restrict__ Wib,
    const float* __restrict__ bib, const float* __restrict__ bhb,
    const float* __restrict__ Wlin,const float* __restrict__ blin,
    const float* __restrict__ hf,  float* __restrict__ out)
{
  const int b = blockIdx.x;
  const int j = threadIdx.x;  // 0..63
  const float* xt = x + ((size_t)b*TT + (TT-1))*7;
  float xv[7];
  #pragma unroll
  for (int k = 0; k < 7; k++) xv[k] = xt[k];

  float g4[4];
  #pragma unroll
  for (int qq = 0; qq < 4; qq++){
    const int g = qq*HH + j;
    float a = bib[g] + bhb[g];
    #pragma unroll
    for (int k = 0; k < 7; k++) a += xv[k]*Wib[g*7+k];
    g4[qq] = a;
  }
  const float iv = fsig(g4[0]);
  const float gv = ftanh(g4[2]);
  const float ov = fsig(g4[3]);
  const float cc = iv*gv;          // f * c0 = 0
  const float hb = ov*ftanh(cc);
  const float hfv = hf[b*HH + j];

  float s[3];
  #pragma unroll
  for (int o = 0; o < 3; o++)
    s[o] = hfv*Wlin[o*128 + j] + hb*Wlin[o*128 + 64 + j];

  #pragma unroll
  for (int o = 0; o < 3; o++){
    float v = s[o];
    #pragma unroll
    for (int m = 32; m >= 1; m >>= 1) v += __shfl_xor(v, m, 64);
    s[o] = v;
  }
  if (j == 0){
    out[b*3+0] = s[0] + blin[0];
    out[b*3+1] = s[1] + blin[1];
    out[b*3+2] = s[2] + blin[2];
  }
}

extern "C" void kernel_launch(void* const* d_in, const int* in_sizes, int n_in,
                              void* d_out, int out_size, void* d_ws, size_t ws_size,
                              hipStream_t stream)
{
  const float* x    = (const float*)d_in[0];
  const float* Wihf = (const float*)d_in[1];
  const float* Whhf = (const float*)d_in[2];
  const float* bihf = (const float*)d_in[3];
  const float* bhhf = (const float*)d_in[4];
  const float* Wihb = (const float*)d_in[5];
  // d_in[6] (W_hh_b) is mathematically unused: backward state starts at zero
  const float* bibb = (const float*)d_in[7];
  const float* bhbb = (const float*)d_in[8];
  const float* Wlin = (const float*)d_in[9];
  const float* blin = (const float*)d_in[10];
  float* out = (float*)d_out;
  float* hf  = (float*)d_ws;   // [512,64] fp32 scratch

  lstm_fwd_kernel<<<BB/2, 64, 0, stream>>>(x, Wihf, Whhf, bihf, bhhf, hf);
  lstm_bwd_lin_kernel<<<BB, 64, 0, stream>>>(x, Wihb, bibb, bhbb, Wlin, blin, hf, out);
}

// Round 16
// 775.537 us; speedup vs baseline: 2.2782x; 2.2782x over previous
//
#include <hip/hip_runtime.h>
#include <hip/hip_bf16.h>

#define TT 2048
#define BB 512
#define HH 64
#define L2E 1.44269504088896340736f

typedef _Float16 h2 __attribute__((ext_vector_type(2)));

__device__ __forceinline__ float frcp(float x){ return __builtin_amdgcn_rcpf(x); }
__device__ __forceinline__ float fexp2(float x){ return __builtin_amdgcn_exp2f(x); }
__device__ __forceinline__ float fsig(float a){ return frcp(1.0f + __expf(-a)); }
__device__ __forceinline__ float ftanh(float a){ return 1.0f - 2.0f*frcp(__expf(2.0f*a)+1.0f); }
__device__ __forceinline__ h2 pk16(float lo, float hi){
  return __builtin_bit_cast(h2, __builtin_amdgcn_cvt_pkrtz(lo, hi));
}
__device__ __forceinline__ int pk16i(float lo, float hi){
  return __builtin_bit_cast(int, pk16(lo, hi));
}
__device__ __forceinline__ float dot2(int w, int hp, float acc){
  return __builtin_amdgcn_fdot2(__builtin_bit_cast(h2, w),
                                __builtin_bit_cast(h2, hp), acc, false);
}

// R15 = R11 (best: 797us total) + unroll-2 software pipelining.
// R11 wall: 993 cyc/step vs ~420 VALU issue + ~310 DS throughput; the
// h publish->readback (~216 cyc) + act chain sit exposed at the iteration
// boundary. Unroll 2 lets the scheduler hoist iteration t+1's x read,
// weight reads and x-proj dots into iteration t's act/publish/readback
// window. x explicitly prefetched one step ahead.
// Structure (R11, proven): lane l owns hidden unit l; i,f weights in
// registers (proven-resident regime); g,o weights in LDS ([gate][kb][lane]
// int4 -> conflict-free ds_read_b128, issued a phase early); h broadcast
// via same-wave LDS round-trip; all activations exp2-based via pre-scaled
// weights.
__global__ void __launch_bounds__(64)
__attribute__((amdgpu_waves_per_eu(1, 2)))
lstm_fwd_kernel(
    const float* __restrict__ x, const float* __restrict__ Wih,
    const float* __restrict__ Whh, const float* __restrict__ bih,
    const float* __restrict__ bhh, float* __restrict__ hout)
{
  const int b = blockIdx.x;
  const int l = threadIdx.x;   // lane == hidden unit

  __shared__ int4 xsf4[TT];          // x as f16 pairs: 16B/step = 32 KB
  __shared__ int4 wgo[2][8][HH];     // g,o weights: [gate][kb][lane] = 16 KB
  __shared__ int4 hlds4[HH/8];       // h as f16[64] = 128 B

  const float* xr = x + (size_t)b*TT*7;

  // ---- one-time: stage x row as f16 pairs (raw; scale lives in wi16) ----
  #pragma unroll 1
  for (int it = 0; it < TT/64; ++it){
    const int t = it*64 + l;
    const float* p = xr + (size_t)t*7;
    int4 v;
    v.x = pk16i(p[0], p[1]);
    v.y = pk16i(p[2], p[3]);
    v.z = pk16i(p[4], p[5]);
    v.w = pk16i(p[6], 0.0f);
    xsf4[t] = v;
  }

  // ---- one-time: stage g,o recurrent weights into LDS (exp2 pre-scaled) ----
  #pragma unroll
  for (int g = 0; g < 2; ++g){
    const int q = 2 + g;                       // 2:g 3:o
    const float sq = (q == 2) ? (-2.0f*L2E) : (-L2E);
    const float4* wr = reinterpret_cast<const float4*>(Whh + (size_t)(q*HH + l)*HH);
    #pragma unroll
    for (int kb = 0; kb < 8; ++kb){
      float4 a = wr[2*kb], b4 = wr[2*kb+1];
      int4 v;
      v.x = pk16i(a.x*sq,  a.y*sq);
      v.y = pk16i(a.z*sq,  a.w*sq);
      v.z = pk16i(b4.x*sq, b4.y*sq);
      v.w = pk16i(b4.z*sq, b4.w*sq);
      wgo[g][kb][l] = v;
    }
  }

  // ---- i,f recurrent weights in registers (64 dwords, pinned) ----
  int wbi[32], wbf[32];
  {
    const float4* wri = reinterpret_cast<const float4*>(Whh + (size_t)(0*HH + l)*HH);
    const float4* wrf = reinterpret_cast<const float4*>(Whh + (size_t)(1*HH + l)*HH);
    #pragma unroll
    for (int k = 0; k < 16; k++){
      float4 a = wri[k];
      wbi[2*k+0] = pk16i(a.x*(-L2E), a.y*(-L2E));
      wbi[2*k+1] = pk16i(a.z*(-L2E), a.w*(-L2E));
      asm volatile("" : "+v"(wbi[2*k+0]), "+v"(wbi[2*k+1]));
    }
    __builtin_amdgcn_sched_barrier(0);
    #pragma unroll
    for (int k = 0; k < 16; k++){
      float4 a = wrf[k];
      wbf[2*k+0] = pk16i(a.x*(-L2E), a.y*(-L2E));
      wbf[2*k+1] = pk16i(a.z*(-L2E), a.w*(-L2E));
      asm volatile("" : "+v"(wbf[2*k+0]), "+v"(wbf[2*k+1]));
    }
    __builtin_amdgcn_sched_barrier(0);
  }

  // ---- input-projection weights as f16 pairs + f32 bias ----
  int wi16[4][4];
  float bias[4];
  #pragma unroll
  for (int q = 0; q < 4; q++){
    const float sq = (q==2) ? (-2.0f*L2E) : (-L2E);
    const int g = q*HH + l;
    wi16[q][0] = pk16i(Wih[g*7+0]*sq, Wih[g*7+1]*sq);
    wi16[q][1] = pk16i(Wih[g*7+2]*sq, Wih[g*7+3]*sq);
    wi16[q][2] = pk16i(Wih[g*7+4]*sq, Wih[g*7+5]*sq);
    wi16[q][3] = pk16i(Wih[g*7+6]*sq, 0.0f);
    bias[q] = (bih[g] + bhh[g])*sq;
  }

  // h_0 = 0 (single wave; per-wave in-order DS makes this visible below)
  if (l < HH/8) hlds4[l] = int4{0,0,0,0};

  float h = 0.0f, c = 0.0f;

  // prologue: first h-read (zeros) + first x
  int hw[32];
  #pragma unroll
  for (int i = 0; i < 8; i++){
    int4 v = hlds4[i];
    hw[4*i+0]=v.x; hw[4*i+1]=v.y; hw[4*i+2]=v.z; hw[4*i+3]=v.w;
  }
  int4 xv = xsf4[0];

  #pragma unroll 2
  for (int t = 0; t < TT; ++t){
    // prefetch next step's x (uniform b128; overlaps this step's compute)
    const int4 xn = xsf4[(t+1) & (TT-1)];

    // issue g-gate weight reads now; i/f dot phase (~128 cyc) covers latency
    int4 g0 = wgo[0][0][l], g1 = wgo[0][1][l], g2 = wgo[0][2][l], g3 = wgo[0][3][l];
    int4 g4 = wgo[0][4][l], g5 = wgo[0][5][l], g6 = wgo[0][6][l], g7 = wgo[0][7][l];

    float a0 = bias[0], a1 = bias[1], a2 = bias[2], a3 = bias[3];

    // i,f dots on register weights (64 dot2)
    #pragma unroll
    for (int k = 0; k < 32; k++){
      a0 = dot2(wbi[k], hw[k], a0);
      a1 = dot2(wbf[k], hw[k], a1);
    }

    // issue o-gate weight reads; g dot phase covers most of their latency
    int4 o0 = wgo[1][0][l], o1 = wgo[1][1][l], o2 = wgo[1][2][l], o3 = wgo[1][3][l];
    int4 o4 = wgo[1][4][l], o5 = wgo[1][5][l], o6 = wgo[1][6][l], o7 = wgo[1][7][l];

    // g dots (32 dot2) on LDS-sourced weights
    #define GDOT(gg, kb) \
      a2 = dot2((gg).x, hw[4*(kb)+0], a2); \
      a2 = dot2((gg).y, hw[4*(kb)+1], a2); \
      a2 = dot2((gg).z, hw[4*(kb)+2], a2); \
      a2 = dot2((gg).w, hw[4*(kb)+3], a2);
    GDOT(g0,0) GDOT(g1,1) GDOT(g2,2) GDOT(g3,3)
    GDOT(g4,4) GDOT(g5,5) GDOT(g6,6) GDOT(g7,7)
    #undef GDOT

    // o dots (32 dot2)
    #define ODOT(oo, kb) \
      a3 = dot2((oo).x, hw[4*(kb)+0], a3); \
      a3 = dot2((oo).y, hw[4*(kb)+1], a3); \
      a3 = dot2((oo).z, hw[4*(kb)+2], a3); \
      a3 = dot2((oo).w, hw[4*(kb)+3], a3);
    ODOT(o0,0) ODOT(o1,1) ODOT(o2,2) ODOT(o3,3)
    ODOT(o4,4) ODOT(o5,5) ODOT(o6,6) ODOT(o7,7)
    #undef ODOT

    // input projection: 16 dot2 on packed x
    a0 = dot2(wi16[0][0], xv.x, a0); a0 = dot2(wi16[0][1], xv.y, a0);
    a0 = dot2(wi16[0][2], xv.z, a0); a0 = dot2(wi16[0][3], xv.w, a0);
    a1 = dot2(wi16[1][0], xv.x, a1); a1 = dot2(wi16[1][1], xv.y, a1);
    a1 = dot2(wi16[1][2], xv.z, a1); a1 = dot2(wi16[1][3], xv.w, a1);
    a2 = dot2(wi16[2][0], xv.x, a2); a2 = dot2(wi16[2][1], xv.y, a2);
    a2 = dot2(wi16[2][2], xv.z, a2); a2 = dot2(wi16[2][3], xv.w, a2);
    a3 = dot2(wi16[3][0], xv.x, a3); a3 = dot2(wi16[3][1], xv.y, a3);
    a3 = dot2(wi16[3][2], xv.z, a3); a3 = dot2(wi16[3][3], xv.w, a3);

    // exp2-based activations (scaling folded into weights/bias)
    const float e0 = fexp2(a0);
    const float e1 = fexp2(a1);
    const float e2 = fexp2(a2);
    const float e3 = fexp2(a3);
    const float iv = frcp(1.0f + e0);
    const float fv = frcp(1.0f + e1);
    const float gv = 2.0f*frcp(1.0f + e2) - 1.0f;
    const float ov = frcp(1.0f + e3);

    c = fv*c + iv*gv;
    const float r = frcp(1.0f + fexp2(c*(-2.0f*L2E)));
    h = 2.0f*ov*r - ov;          // ov * tanh(c)

    // publish h_t, then issue next step's h-reads (per-wave in-order DS)
    reinterpret_cast<unsigned short*>(hlds4)[l] =
        __builtin_bit_cast(unsigned short, (_Float16)h);
    #pragma unroll
    for (int i = 0; i < 8; i++){
      int4 v = hlds4[i];
      hw[4*i+0]=v.x; hw[4*i+1]=v.y; hw[4*i+2]=v.z; hw[4*i+3]=v.w;
    }
    xv = xn;
  }
  hout[b*HH + l] = h;
}

// Backward direction contributes only ONE step (scan reverse=True: output at
// t=T-1 is the first reverse step from zero state => W_hh_b unused, c = i*g).
// Fused with the final linear layer.
__global__ __launch_bounds__(64, 1) void lstm_bwd_lin_kernel(
    const float* __restrict__ x,   const float* __restrict__ Wib,
    const float* __restrict__ bib, const float* __restrict__ bhb,
    const float* __restrict__ Wlin,const float* __restrict__ blin,
    const float* __restrict__ hf,  float* __restrict__ out)
{
  const int b = blockIdx.x;
  const int j = threadIdx.x;  // 0..63
  const float* xt = x + ((size_t)b*TT + (TT-1))*7;
  float xv[7];
  #pragma unroll
  for (int k = 0; k < 7; k++) xv[k] = xt[k];

  float g4[4];
  #pragma unroll
  for (int qq = 0; qq < 4; qq++){
    const int g = qq*HH + j;
    float a = bib[g] + bhb[g];
    #pragma unroll
    for (int k = 0; k < 7; k++) a += xv[k]*Wib[g*7+k];
    g4[qq] = a;
  }
  const float iv = fsig(g4[0]);
  const float gv = ftanh(g4[2]);
  const float ov = fsig(g4[3]);
  const float cc = iv*gv;          // f * c0 = 0
  const float hb = ov*ftanh(cc);
  const float hfv = hf[b*HH + j];

  float s[3];
  #pragma unroll
  for (int o = 0; o < 3; o++)
    s[o] = hfv*Wlin[o*128 + j] + hb*Wlin[o*128 + 64 + j];

  #pragma unroll
  for (int o = 0; o < 3; o++){
    float v = s[o];
    #pragma unroll
    for (int m = 32; m >= 1; m >>= 1) v += __shfl_xor(v, m, 64);
    s[o] = v;
  }
  if (j == 0){
    out[b*3+0] = s[0] + blin[0];
    out[b*3+1] = s[1] + blin[1];
    out[b*3+2] = s[2] + blin[2];
  }
}

extern "C" void kernel_launch(void* const* d_in, const int* in_sizes, int n_in,
                              void* d_out, int out_size, void* d_ws, size_t ws_size,
                              hipStream_t stream)
{
  const float* x    = (const float*)d_in[0];
  const float* Wihf = (const float*)d_in[1];
  const float* Whhf = (const float*)d_in[2];
  const float* bihf = (const float*)d_in[3];
  const float* bhhf = (const float*)d_in[4];
  const float* Wihb = (const float*)d_in[5];
  // d_in[6] (W_hh_b) is mathematically unused: backward state starts at zero
  const float* bibb = (const float*)d_in[7];
  const float* bhbb = (const float*)d_in[8];
  const float* Wlin = (const float*)d_in[9];
  const float* blin = (const float*)d_in[10];
  float* out = (float*)d_out;
  float* hf  = (float*)d_ws;   // [512,64] fp32 scratch

  lstm_fwd_kernel<<<BB, 64, 0, stream>>>(x, Wihf, Whhf, bihf, bhhf, hf);
  lstm_bwd_lin_kernel<<<BB, 64, 0, stream>>>(x, Wihb, bibb, bhbb, Wlin, blin, hf, out);
}